// Round 9
// baseline (1543.178 us; speedup 1.0000x reference)
//
#include <hip/hip_runtime.h>
#include <math.h>

#define N_CELL 400000
#define N_NET  100000
#define E_PIN  1600000
#define E2     400000

// ================= CSR build =================

__global__ void __launch_bounds__(256) k_hist(
    const int* __restrict__ src, const int* __restrict__ dst,
    int* __restrict__ cell_deg, int* __restrict__ net_deg)
{
    int e = blockIdx.x * 256 + threadIdx.x;
    if (e >= E_PIN) return;
    atomicAdd(&net_deg[dst[e]], 1);
    atomicAdd(&cell_deg[src[e]], 1);
}

__global__ void __launch_bounds__(256) k_alloc(
    const int* __restrict__ deg, int* __restrict__ ptr, int* __restrict__ cur,
    int* __restrict__ cursor, int n)
{
    __shared__ int s[256];
    __shared__ int base;
    int tid = threadIdx.x;
    int i = blockIdx.x * 256 + tid;
    int d = (i < n) ? deg[i] : 0;
    int v = d;
    s[tid] = v;
    __syncthreads();
    for (int o = 1; o < 256; o <<= 1) {
        int t = (tid >= o) ? s[tid - o] : 0;
        __syncthreads();
        v += t;
        s[tid] = v;
        __syncthreads();
    }
    if (tid == 255) base = atomicAdd(cursor, v);
    __syncthreads();
    if (i < n) {
        int p = base + v - d;
        ptr[i] = p;
        cur[i] = p;
    }
}

__global__ void __launch_bounds__(256) k_fill(
    const int* __restrict__ src, const int* __restrict__ dst,
    int* __restrict__ net_cur, int* __restrict__ cell_cur,
    int* __restrict__ csr_net_cell, int* __restrict__ csr_cell_net,
    int* __restrict__ edge_slot)
{
    int e = blockIdx.x * 256 + threadIdx.x;
    if (e >= E_PIN) return;
    int s = src[e], d = dst[e];
    int p = atomicAdd(&net_cur[d], 1);
    csr_net_cell[p] = s;
    int q = atomicAdd(&cell_cur[s], 1);
    csr_cell_net[q] = d;
    edge_slot[e] = q;
}

// ==== precompute projection vectors ====
// wd_d (d=0..4): Wdis[0:64], Wdis[64:128], Wdef[0:64], Wdef[64:128], Wdef[128:192]
// u_all[d][i] = sum_j Wself[i*64+j] * wd_d[j]      (5x64)
// v_all[d][i] = sum_j Wneigh[i*64+j] * wd_d[j]     (d<5); v5=Wdis[128:], v6=Wdef[192:256], v7=Wdef[256:320]
// bsd[d] = b_sage . wd_d
__global__ void __launch_bounds__(256) k_prep(
    const float* __restrict__ Wself, const float* __restrict__ Wneigh,
    const float* __restrict__ Wdis, const float* __restrict__ Wdef,
    const float* __restrict__ bsage,
    float* __restrict__ u_all, float* __restrict__ v_all, float* __restrict__ bsd)
{
    __shared__ float wd[5][64];
    int tid = threadIdx.x;
    if (tid < 320) {
        int d = tid >> 6, i = tid & 63;
        wd[d][i] = (d < 2) ? Wdis[d * 64 + i] : Wdef[(d - 2) * 64 + i];
    }
    __syncthreads();
    for (int o = tid; o < 320; o += 256) {
        int d = o >> 6, i = o & 63;
        float a = 0.0f, bvec = 0.0f;
        for (int j = 0; j < 64; ++j) {
            a += Wself[i * 64 + j] * wd[d][j];
            bvec += Wneigh[i * 64 + j] * wd[d][j];
        }
        u_all[o] = a;
        v_all[o] = bvec;
    }
    if (tid < 64) {
        v_all[5 * 64 + tid] = Wdis[128 + tid];
        v_all[6 * 64 + tid] = Wdef[192 + tid];
        v_all[7 * 64 + tid] = Wdef[256 + tid];
    }
    if (tid < 5) {
        float a = 0.0f;
        for (int j = 0; j < 64; ++j) a += bsage[j] * wd[tid][j];
        bsd[tid] = a;
    }
}

// ==== per-pin edge weight, scattered into cell-CSR slot order ====
__global__ void __launch_bounds__(256) k_ew(
    const float* __restrict__ pin_feat,
    const float* __restrict__ W_pin, const float* __restrict__ b_pin,
    const float* __restrict__ W_ew, const float* __restrict__ b_ew,
    const int* __restrict__ edge_slot,
    float* __restrict__ ew_csr)
{
    __shared__ float Wp[8 * 16];
    __shared__ float bp[16];
    __shared__ float We[16];
    __shared__ float be_s;
    int tid = threadIdx.x;
    if (tid < 128) Wp[tid] = W_pin[tid];
    if (tid < 16) { bp[tid] = b_pin[tid]; We[tid] = W_ew[tid]; }
    if (tid == 0) be_s = b_ew[0];
    __syncthreads();
    int e = blockIdx.x * 256 + tid;
    if (e >= E_PIN) return;
    float p[8];
    #pragma unroll
    for (int k = 0; k < 8; ++k) p[k] = pin_feat[e * 8 + k];
    float acc = be_s;
    #pragma unroll
    for (int j = 0; j < 16; ++j) {
        float h = bp[j];
        #pragma unroll
        for (int k = 0; k < 8; ++k) h += p[k] * Wp[k * 16 + j];
        acc += tanhf(h) * We[j];
    }
    ew_csr[edge_slot[e]] = tanhf(acc);
}

// ==== fused NET kernel -> netpack[net][16]:
// [0:8] raw net_feat, [8:13] s_d = hn.v_d, [13..15] = hn.{Wdis_net,Wdef_gf,Wdef_fs}
__global__ void __launch_bounds__(256, 4) k_net(
    const float* __restrict__ net_feat, const float* __restrict__ cell_feat,
    const int* __restrict__ net_ptr, const int* __restrict__ net_deg,
    const int* __restrict__ csr_cell,
    const float* __restrict__ W_net, const float* __restrict__ b_net,
    const float* __restrict__ v_all,
    float* __restrict__ netpack)
{
    __shared__ float xs24[64 * 25];
    __shared__ float Ws24[24 * 64];
    __shared__ float HN[64 * 68];      // stride 68: float4-aligned, rotated reads
    __shared__ float V8[8 * 64];
    __shared__ float bs[64];

    int tid = threadIdx.x;
    int w = tid >> 6, l = tid & 63;
    int tile = blockIdx.x * 64;

    for (int i = tid; i < 1536; i += 256) Ws24[i] = W_net[i];
    for (int i = tid; i < 512; i += 256) V8[i] = v_all[i];
    if (tid < 64) bs[tid] = b_net[tid];

    // P1: gather cell_feat mean/max, unroll-4; write raw feats to netpack
    int g = l >> 3, k = l & 7;
    #pragma unroll
    for (int p = 0; p < 2; ++p) {
        int rl = p * 32 + w * 8 + g;
        int row = tile + rl;
        int base = 0, deg = 0;
        if (row < N_NET) { base = net_ptr[row]; deg = net_deg[row]; }
        float sum = 0.0f, mx = -INFINITY;
        int j = 0;
        for (; j + 4 <= deg; j += 4) {
            int i0 = csr_cell[base + j], i1 = csr_cell[base + j + 1];
            int i2 = csr_cell[base + j + 2], i3 = csr_cell[base + j + 3];
            float v0 = cell_feat[i0 * 8 + k];
            float v1 = cell_feat[i1 * 8 + k];
            float v2 = cell_feat[i2 * 8 + k];
            float v3 = cell_feat[i3 * 8 + k];
            sum += (v0 + v1) + (v2 + v3);
            mx = fmaxf(fmaxf(fmaxf(mx, v0), fmaxf(v1, v2)), v3);
        }
        for (; j < deg; ++j) {
            float v = cell_feat[csr_cell[base + j] * 8 + k];
            sum += v;
            mx = fmaxf(mx, v);
        }
        float inv = (deg > 0) ? 1.0f / (float)deg : 1.0f;
        float sf = (row < N_NET) ? net_feat[row * 8 + k] : 0.0f;
        xs24[rl * 25 + k] = sf;
        xs24[rl * 25 + 8 + k] = sum * inv;
        xs24[rl * 25 + 16 + k] = (deg > 0) ? mx : 0.0f;
        if (row < N_NET) netpack[(size_t)row * 16 + k] = sf;
    }
    __syncthreads();

    // P2: hn = tanh(xs24 @ W_net + b) -> HN (float4 stores)
    {
        int rg = l >> 2, cc = l & 3, c0 = w * 16 + cc * 4;
        float acc[4][4];
        float4 b4 = *(const float4*)&bs[c0];
        #pragma unroll
        for (int i = 0; i < 4; ++i) {
            acc[i][0] = b4.x; acc[i][1] = b4.y; acc[i][2] = b4.z; acc[i][3] = b4.w;
        }
        for (int kk = 0; kk < 24; ++kk) {
            float4 wv = *(const float4*)&Ws24[kk * 64 + c0];
            #pragma unroll
            for (int i = 0; i < 4; ++i) {
                float x = xs24[(rg * 4 + i) * 25 + kk];
                acc[i][0] += x * wv.x; acc[i][1] += x * wv.y;
                acc[i][2] += x * wv.z; acc[i][3] += x * wv.w;
            }
        }
        #pragma unroll
        for (int i = 0; i < 4; ++i)
            *(float4*)&HN[(rg * 4 + i) * 68 + c0] =
                make_float4(tanhf(acc[i][0]), tanhf(acc[i][1]),
                            tanhf(acc[i][2]), tanhf(acc[i][3]));
    }
    __syncthreads();

    // P3: 8 dots per row (rotated reads: conflict-free)
    #pragma unroll
    for (int pass = 0; pass < 2; ++pass) {
        int d = (tid >> 6) + pass * 4;
        int row = tid & 63;
        float a = 0.0f;
        for (int t = 0; t < 64; ++t) {
            int kk = (row + t) & 63;
            a += HN[row * 68 + kk] * V8[d * 64 + kk];
        }
        int grow = tile + row;
        if (grow < N_NET) netpack[(size_t)grow * 16 + 8 + d] = a;
    }
}

// ==== fused CELL kernel -> cellpack[cell][8]:
// d0..d4 = hc.u_d + mean(ew*s_d) + bsd_d ; [5]=sx [6]=sy [7]=0
__global__ void __launch_bounds__(256, 4) k_cell(
    const float* __restrict__ cell_feat, const float* __restrict__ cell_size,
    const int* __restrict__ cell_ptr, const int* __restrict__ cell_deg,
    const int* __restrict__ csr_net, const float* __restrict__ ew_csr,
    const float* __restrict__ netpack,
    const float* __restrict__ W_cell, const float* __restrict__ b_cell,
    const float* __restrict__ u_all, const float* __restrict__ bsd,
    float* __restrict__ cellpack)
{
    __shared__ float xs24[64 * 25];
    __shared__ float Ws24[24 * 64];
    __shared__ float HC[64 * 68];      // stride 68
    __shared__ float U5[5 * 64];
    __shared__ float MS[64 * 9];       // stride 9: conflict-free read by (row,d)
    __shared__ float bs[64];

    int tid = threadIdx.x;
    int w = tid >> 6, l = tid & 63;
    int tile = blockIdx.x * 64;        // N_CELL/64 exact

    for (int i = tid; i < 1536; i += 256) Ws24[i] = W_cell[i];
    for (int i = tid; i < 320; i += 256) U5[i] = u_all[i];
    if (tid < 64) bs[tid] = b_cell[tid];

    // P1: gather netpack (raw feat k + s_k), unroll-4
    int g = l >> 3, k = l & 7;
    #pragma unroll
    for (int p = 0; p < 2; ++p) {
        int rl = p * 32 + w * 8 + g;
        int row = tile + rl;
        int base = cell_ptr[row], deg = cell_deg[row];
        float sum = 0.0f, mx = -INFINITY, sacc = 0.0f;
        int j = 0;
        for (; j + 4 <= deg; j += 4) {
            int slot = base + j;
            int n0 = csr_net[slot], n1 = csr_net[slot + 1];
            int n2 = csr_net[slot + 2], n3 = csr_net[slot + 3];
            float w0 = ew_csr[slot], w1 = ew_csr[slot + 1];
            float w2 = ew_csr[slot + 2], w3 = ew_csr[slot + 3];
            float f0 = netpack[(size_t)n0 * 16 + k];
            float f1 = netpack[(size_t)n1 * 16 + k];
            float f2 = netpack[(size_t)n2 * 16 + k];
            float f3 = netpack[(size_t)n3 * 16 + k];
            float s0 = netpack[(size_t)n0 * 16 + 8 + k];
            float s1 = netpack[(size_t)n1 * 16 + 8 + k];
            float s2 = netpack[(size_t)n2 * 16 + 8 + k];
            float s3 = netpack[(size_t)n3 * 16 + 8 + k];
            sum += (f0 + f1) + (f2 + f3);
            mx = fmaxf(fmaxf(fmaxf(mx, f0), fmaxf(f1, f2)), f3);
            sacc += (w0 * s0 + w1 * s1) + (w2 * s2 + w3 * s3);
        }
        for (; j < deg; ++j) {
            int slot = base + j;
            int n = csr_net[slot];
            float wt = ew_csr[slot];
            float f = netpack[(size_t)n * 16 + k];
            sum += f;
            mx = fmaxf(mx, f);
            sacc += wt * netpack[(size_t)n * 16 + 8 + k];
        }
        float inv = (deg > 0) ? 1.0f / (float)deg : 1.0f;
        xs24[rl * 25 + k] = cell_feat[row * 8 + k];
        xs24[rl * 25 + 8 + k] = sum * inv;
        xs24[rl * 25 + 16 + k] = (deg > 0) ? mx : 0.0f;
        MS[rl * 9 + k] = sacc * inv;   // only k<5 consumed
    }
    __syncthreads();

    // P2: hc = tanh(xs24 @ W_cell + b) -> HC (float4 stores)
    {
        int rg = l >> 2, cc = l & 3, c0 = w * 16 + cc * 4;
        float acc[4][4];
        float4 b4 = *(const float4*)&bs[c0];
        #pragma unroll
        for (int i = 0; i < 4; ++i) {
            acc[i][0] = b4.x; acc[i][1] = b4.y; acc[i][2] = b4.z; acc[i][3] = b4.w;
        }
        for (int kk = 0; kk < 24; ++kk) {
            float4 wv = *(const float4*)&Ws24[kk * 64 + c0];
            #pragma unroll
            for (int i = 0; i < 4; ++i) {
                float x = xs24[(rg * 4 + i) * 25 + kk];
                acc[i][0] += x * wv.x; acc[i][1] += x * wv.y;
                acc[i][2] += x * wv.z; acc[i][3] += x * wv.w;
            }
        }
        #pragma unroll
        for (int i = 0; i < 4; ++i)
            *(float4*)&HC[(rg * 4 + i) * 68 + c0] =
                make_float4(tanhf(acc[i][0]), tanhf(acc[i][1]),
                            tanhf(acc[i][2]), tanhf(acc[i][3]));
    }
    __syncthreads();

    // P3: 5 dots + sizes (rotated reads)
    {
        int d = tid >> 6;              // pass 1: d = 0..3
        int row = tid & 63;
        float a = 0.0f;
        for (int t = 0; t < 64; ++t) {
            int kk = (row + t) & 63;
            a += HC[row * 68 + kk] * U5[d * 64 + kk];
        }
        size_t gbase = (size_t)(tile + row) * 8;
        cellpack[gbase + d] = a + MS[row * 9 + d] + bsd[d];
    }
    {
        int d = tid >> 6;
        int row = tid & 63;
        size_t gbase = (size_t)(tile + row) * 8;
        if (d == 0) {
            float a = 0.0f;
            for (int t = 0; t < 64; ++t) {
                int kk = (row + t) & 63;
                a += HC[row * 68 + kk] * U5[4 * 64 + kk];
            }
            cellpack[gbase + 4] = a + MS[row * 9 + 4] + bsd[4];
        } else if (d == 1) {
            cellpack[gbase + 5] = cell_size[(size_t)(tile + row) * 2];
        } else if (d == 2) {
            cellpack[gbase + 6] = cell_size[(size_t)(tile + row) * 2 + 1];
        } else {
            cellpack[gbase + 7] = 0.0f;
        }
    }
}

// ============ edge readout: one thread per edge, scalar packs ============
__global__ void __launch_bounds__(256) k_edge(
    const float* __restrict__ cellpack, const float* __restrict__ netpack,
    const int* __restrict__ fa, const int* __restrict__ so, const int* __restrict__ gf,
    const int* __restrict__ fsn, const int* __restrict__ gfn,
    const float* __restrict__ b_dis, const float* __restrict__ b_def,
    float* __restrict__ out)
{
    int e = blockIdx.x * 256 + threadIdx.x;
    if (e >= E2) return;
    int f = fa[e], s = so[e], g = gf[e], nf = fsn[e], ng = gfn[e];
    const float4* cf = (const float4*)(cellpack + (size_t)f * 8);
    float4 f0 = cf[0], f1 = cf[1];
    const float4* cs = (const float4*)(cellpack + (size_t)s * 8);
    float4 s0 = cs[0], s1 = cs[1];
    float g2 = cellpack[(size_t)g * 8 + 2];
    float4 nfp = *(const float4*)(netpack + (size_t)nf * 16 + 12); // [12..15]
    float ng_t = netpack[(size_t)ng * 16 + 14];
    float dis = f0.x + s0.y + nfp.y + b_dis[0];                 // d0_f + d1_s + t_dis
    float defl = g2 + f0.w + s1.x + ng_t + nfp.w + b_def[0];    // d2_g + d3_f + d4_s + t_gf + t_fs
    float o1 = expf(-2.0f + 15.0f * tanhf(dis));
    float bx = (f1.y + s1.y) * 0.5f;
    float by = (f1.z + s1.z) * 0.5f;
    out[e] = o1 + fminf(bx, by);
    out[E2 + e] = tanhf(defl) * 6.28318530717958647692f;
}

extern "C" void kernel_launch(void* const* d_in, const int* in_sizes, int n_in,
                              void* d_out, int out_size, void* d_ws, size_t ws_size,
                              hipStream_t stream)
{
    const float* cell_feat = (const float*)d_in[0];
    const float* net_feat  = (const float*)d_in[1];
    const float* pin_feat  = (const float*)d_in[2];
    const float* cell_size = (const float*)d_in[3];
    const float* W_cell = (const float*)d_in[4];
    const float* b_cell = (const float*)d_in[5];
    const float* W_net  = (const float*)d_in[6];
    const float* b_net  = (const float*)d_in[7];
    const float* W_pin  = (const float*)d_in[8];
    const float* b_pin  = (const float*)d_in[9];
    const float* W_ew   = (const float*)d_in[10];
    const float* b_ew   = (const float*)d_in[11];
    const float* W_self = (const float*)d_in[12];
    const float* W_neigh= (const float*)d_in[13];
    const float* b_sage = (const float*)d_in[14];
    const float* W_dis  = (const float*)d_in[15];
    const float* b_dis  = (const float*)d_in[16];
    const float* W_def  = (const float*)d_in[17];
    const float* b_def  = (const float*)d_in[18];
    const int* pins_src = (const int*)d_in[19];
    const int* pins_dst = (const int*)d_in[20];
    const int* fathers  = (const int*)d_in[21];
    const int* sons     = (const int*)d_in[22];
    const int* grandf   = (const int*)d_in[23];
    const int* fs_nets  = (const int*)d_in[24];
    const int* gf_nets  = (const int*)d_in[25];

    char* ws = (char*)d_ws;
    size_t off = 0;
    auto alloc = [&](size_t bytes) -> void* {
        void* p = ws + off;
        off += (bytes + 255) & ~(size_t)255;
        return p;
    };
    int* cursors   = (int*)alloc(2 * 4);
    int* net_deg   = (int*)alloc((size_t)N_NET * 4);
    int* cell_deg  = (int*)alloc((size_t)N_CELL * 4);
    size_t zero_bytes = off;
    int* net_ptr   = (int*)alloc((size_t)N_NET * 4);
    int* net_cur   = (int*)alloc((size_t)N_NET * 4);
    int* cell_ptr  = (int*)alloc((size_t)N_CELL * 4);
    int* cell_cur  = (int*)alloc((size_t)N_CELL * 4);
    int* csr_net_cell = (int*)alloc((size_t)E_PIN * 4);
    int* csr_cell_net = (int*)alloc((size_t)E_PIN * 4);
    int* edge_slot    = (int*)alloc((size_t)E_PIN * 4);
    float* ew_csr   = (float*)alloc((size_t)E_PIN * 4);
    float* netpack  = (float*)alloc((size_t)N_NET * 16 * 4);
    float* cellpack = (float*)alloc((size_t)N_CELL * 8 * 4);
    float* u_all    = (float*)alloc(5 * 64 * 4);
    float* v_all    = (float*)alloc(8 * 64 * 4);
    float* bsd      = (float*)alloc(8 * 4);
    if (off > ws_size) return;   // fail loudly (absmax), don't fault

    hipMemsetAsync(d_ws, 0, zero_bytes, stream);

    // projection vectors (independent of CSR)
    k_prep<<<1, 256, 0, stream>>>(W_self, W_neigh, W_dis, W_def, b_sage,
                                  u_all, v_all, bsd);

    // CSR build
    k_hist<<<(E_PIN + 255) / 256, 256, 0, stream>>>(pins_src, pins_dst, cell_deg, net_deg);
    k_alloc<<<(N_NET + 255) / 256, 256, 0, stream>>>(net_deg, net_ptr, net_cur, &cursors[0], N_NET);
    k_alloc<<<(N_CELL + 255) / 256, 256, 0, stream>>>(cell_deg, cell_ptr, cell_cur, &cursors[1], N_CELL);
    k_fill<<<(E_PIN + 255) / 256, 256, 0, stream>>>(
        pins_src, pins_dst, net_cur, cell_cur, csr_net_cell, csr_cell_net, edge_slot);

    // edge weights into cell-CSR slot order
    k_ew<<<(E_PIN + 255) / 256, 256, 0, stream>>>(
        pin_feat, W_pin, b_pin, W_ew, b_ew, edge_slot, ew_csr);

    // fused net-side -> netpack
    k_net<<<(N_NET + 63) / 64, 256, 0, stream>>>(
        net_feat, cell_feat, net_ptr, net_deg, csr_net_cell,
        W_net, b_net, v_all, netpack);

    // fused cell-side -> cellpack
    k_cell<<<N_CELL / 64, 256, 0, stream>>>(
        cell_feat, cell_size, cell_ptr, cell_deg, csr_cell_net, ew_csr,
        netpack, W_cell, b_cell, u_all, bsd, cellpack);

    // edge readout
    k_edge<<<(E2 + 255) / 256, 256, 0, stream>>>(
        cellpack, netpack, fathers, sons, grandf, fs_nets, gf_nets,
        b_dis, b_def, (float*)d_out);
}